// Round 2
// 120.116 us; speedup vs baseline: 1.0424x; 1.0424x over previous
//
#include <hip/hip_runtime.h>

// SliceNApply: bilateral-grid trilinear slice + per-pixel 3x4 affine apply.
// FP32 tensors. B=4, C=12, D=8, Hg=Wg=16, H=W=1024.
//
// R8: R7 retry — f16 z-pair packing + v_dot2_f32_f16 consumption.
//   Compile fix only: half2v is now decltype(__builtin_amdgcn_cvt_pkrtz),
//   i.e. __fp16 ext_vector_type(2), matching both cvt_pkrtz and fdot2
//   builtin signatures on this clang (R7 used _Float16 -> type error).
//   Theory (R7): bf16 unpack costs 1 VALU per product (192 ops/px);
//   fdot2 does wl*lo + wh*hi + acc in ONE instr with f32 accumulate ->
//   apply VALU 192 -> ~60 ops/px, and f16 (10-bit mantissa) beats bf16
//   (8-bit) on precision -> absmax should drop ~4x.
//   Kept (verified R2-R6): z-pair packing (12 ds_read_b128/px), quadrant
//   waves + ZSTRIDE=132 -> SQ_LDS_BANK_CONFLICT ~ 0, zero local arrays /
//   all-scalar compute phase (scratch-proof), __launch_bounds__(256,3).

#define ZSTRIDE 132   // 9 cells * 12 ch = 108 dwords + 24 pad (132 % 32 == 4)

using half2v = decltype(__builtin_amdgcn_cvt_pkrtz(0.0f, 0.0f));

static __device__ __forceinline__ half2v pkrtz(float lo, float hi) {
    return __builtin_amdgcn_cvt_pkrtz(lo, hi);   // v_cvt_pkrtz_f16_f32
}
static __device__ __forceinline__ half2v u2h2(unsigned int u) {
    return __builtin_bit_cast(half2v, u);
}
static __device__ __forceinline__ unsigned int h2u(half2v h) {
    return __builtin_bit_cast(unsigned int, h);
}

#if __has_builtin(__builtin_amdgcn_fdot2)
#define DOT2(d, wp, acc) __builtin_amdgcn_fdot2(u2h2(d), (wp), (acc), false)
#else
// fallback: mixed-precision fma (compiler forms v_fma_mix_f32)
static __device__ __forceinline__ float dot2_sw(unsigned int d, half2v wp, float acc) {
    half2v h = u2h2(d);
    return fmaf((float)wp.x, (float)h.x, fmaf((float)wp.y, (float)h.y, acc));
}
#define DOT2(d, wp, acc) dot2_sw((d), (wp), (acc))
#endif

// one corner's 4-channel dual-z dot-accumulate (all scalar refs)
static __device__ __forceinline__ void corner_dot(
    const unsigned int* __restrict__ cp, half2v wp,
    float& a0, float& a1, float& a2, float& a3)
{
    const uint4 d = *reinterpret_cast<const uint4*>(cp);
    a0 = DOT2(d.x, wp, a0);
    a1 = DOT2(d.y, wp, a1);
    a2 = DOT2(d.z, wp, a2);
    a3 = DOT2(d.w, wp, a3);
}

__global__ __launch_bounds__(256, 3) void slice_apply(
    const float* __restrict__ grid,   // [4][12][8][16][16]
    const float* __restrict__ guide,  // [4][1][1024][1024]
    const float* __restrict__ fr,     // [4][3][1024][1024]
    float* __restrict__ out)          // [4][3][1024][1024]
{
    __shared__ __align__(16) unsigned int lds[8 * ZSTRIDE];

    const int b     = blockIdx.y;
    const int tileX = blockIdx.x & 15;
    const int tileY = blockIdx.x >> 4;
    const int t     = threadIdx.x;

    // ---- stage grid slice into LDS, z-pair packed as f16x2 ----
    {
        const int py0 = min(max(tileY - 1, 0), 15);
        const int py1 = tileY;
        const int py2 = min(tileY + 1, 15);
        const int px0 = min(max(tileX - 1, 0), 15);
        const int px1 = tileX;
        const int px2 = min(tileX + 1, 15);
        for (int e = t; e < 8 * 9 * 12; e += 256) {
            const int c    = e % 12;
            const int cell = (e / 12) % 9;
            const int s    = e / 108;
            const int s2   = min(s + 1, 7);
            const int gy3  = cell / 3;
            const int gx3  = cell % 3;
            const int ry = (gy3 == 0) ? py0 : ((gy3 == 1) ? py1 : py2);
            const int rx = (gx3 == 0) ? px0 : ((gx3 == 1) ? px1 : px2);
            const int cb = (b * 12 + c) * 8;
            const int sp = ry * 16 + rx;
            const float lo = grid[(cb + s)  * 256 + sp];
            const float hi = grid[(cb + s2) * 256 + sp];
            lds[s * ZSTRIDE + cell * 12 + c] = h2u(pkrtz(lo, hi));
        }
    }
    __syncthreads();

    // wave = quadrant (32x32 px); lane -> 1 px: 32 lanes span x, 2 sub-rows
    const int w   = t >> 6;
    const int l   = t & 63;
    const int by  = w >> 1;          // wave-uniform
    const int bx  = w & 1;           // wave-uniform
    const int lxq = l & 31;          // x within quadrant
    const int sub = l >> 5;          // row-pair select

    const int xg = tileX * 64 + bx * 32 + lxq;          // global x
    const float wx = ((float)(bx * 32 + lxq) + 0.5f) * 0.015625f +
                     (0.5f - (float)bx);
    const float u1 = wx, u0 = 1.0f - wx;

    // corner dword offsets: four named scalars (NOT an array)
    const int cof0 = ((by + 0) * 3 + (bx + 0)) * 12;
    const int cof1 = ((by + 0) * 3 + (bx + 1)) * 12;
    const int cof2 = ((by + 1) * 3 + (bx + 0)) * 12;
    const int cof3 = ((by + 1) * 3 + (bx + 1)) * 12;

    const int ybase = tileY * 64 + by * 32;

    for (int i = 0; i < 16; ++i) {
        const int ly = by * 32 + i * 2 + sub;           // tile-local y
        const int y  = ybase - by * 32 + ly;            // = tileY*64 + ly
        const float wy = ((float)ly + 0.5f) * 0.015625f + (0.5f - (float)by);
        const float v1 = wy, v0 = 1.0f - wy;

        const int gofs = (b * 1024 + y) * 1024 + xg;
        const int fofs = ((b * 3) * 1024 + y) * 1024 + xg;

        const float g  = guide[gofs];
        const float f0 = fr[fofs];
        const float f1 = fr[fofs + 1048576];
        const float f2 = fr[fofs + 2097152];

        const float gz = g * 8.0f - 0.5f;
        int s = (int)floorf(gz);
        s = min(max(s, 0), 7);
        const float wz = fmaxf(gz - (float)s, 0.0f);
        const float zl = 1.0f - wz, zh = wz;
        const unsigned int* sb = &lds[s * ZSTRIDE];

        const float w00 = v0 * u0, w01 = v0 * u1;
        const float w10 = v1 * u0, w11 = v1 * u1;
        // packed (z-lo, z-hi) corner weights: one v_cvt_pkrtz each
        const half2v wp0 = pkrtz(w00 * zl, w00 * zh);
        const half2v wp1 = pkrtz(w01 * zl, w01 * zh);
        const half2v wp2 = pkrtz(w10 * zl, w10 * zh);
        const half2v wp3 = pkrtz(w11 * zl, w11 * zh);

        float o0, o1, o2;
        {
            float a0 = 0.f, a1 = 0.f, a2 = 0.f, a3 = 0.f;
            corner_dot(sb + cof0, wp0, a0, a1, a2, a3);
            corner_dot(sb + cof1, wp1, a0, a1, a2, a3);
            corner_dot(sb + cof2, wp2, a0, a1, a2, a3);
            corner_dot(sb + cof3, wp3, a0, a1, a2, a3);
            o0 = fmaf(a0, f0, fmaf(a1, f1, fmaf(a2, f2, a3)));
        }
        {
            float a0 = 0.f, a1 = 0.f, a2 = 0.f, a3 = 0.f;
            corner_dot(sb + cof0 + 4, wp0, a0, a1, a2, a3);
            corner_dot(sb + cof1 + 4, wp1, a0, a1, a2, a3);
            corner_dot(sb + cof2 + 4, wp2, a0, a1, a2, a3);
            corner_dot(sb + cof3 + 4, wp3, a0, a1, a2, a3);
            o1 = fmaf(a0, f0, fmaf(a1, f1, fmaf(a2, f2, a3)));
        }
        {
            float a0 = 0.f, a1 = 0.f, a2 = 0.f, a3 = 0.f;
            corner_dot(sb + cof0 + 8, wp0, a0, a1, a2, a3);
            corner_dot(sb + cof1 + 8, wp1, a0, a1, a2, a3);
            corner_dot(sb + cof2 + 8, wp2, a0, a1, a2, a3);
            corner_dot(sb + cof3 + 8, wp3, a0, a1, a2, a3);
            o2 = fmaf(a0, f0, fmaf(a1, f1, fmaf(a2, f2, a3)));
        }

        out[fofs]           = o0;
        out[fofs + 1048576] = o1;
        out[fofs + 2097152] = o2;
    }
}

extern "C" void kernel_launch(void* const* d_in, const int* in_sizes, int n_in,
                              void* d_out, int out_size, void* d_ws, size_t ws_size,
                              hipStream_t stream) {
    const float* grid  = (const float*)d_in[0];
    const float* guide = (const float*)d_in[1];
    const float* fr    = (const float*)d_in[2];
    float* out = (float*)d_out;

    dim3 g(256, 4);   // 16x16 tiles of 64x64 px, 4 batches
    dim3 blk(256);
    hipLaunchKernelGGL(slice_apply, g, blk, 0, stream, grid, guide, fr, out);
}

// Round 3
// 117.461 us; speedup vs baseline: 1.0660x; 1.0226x over previous
//
#include <hip/hip_runtime.h>

// SliceNApply: bilateral-grid trilinear slice + per-pixel 3x4 affine apply.
// FP32 tensors. B=4, C=12, D=8, Hg=Wg=16, H=W=1024.
//
// R9: break the per-iteration guide->s->LDS dependency chain.
//   Evidence: R8 kernel ~36 us vs overlap floor ~20 us (HBM 19 / LDS 15 /
//   VALU 6): pipes are serialized by the chain guide-load -> s -> LDS read
//   (address depends on loaded value) x16 iters, 4 waves/SIMD can't hide.
//   Fix: (a) explicit 1-iter software prefetch of guide/fr; (b) 2 px/lane
//   via float2 loads/stores -> 8 chains instead of 16, ~2x busy work per
//   chain, half the global instructions, 8B/lane coalescing sweet spot.
//   __launch_bounds__(256,4): VGPR cap 128 (R6 measured 84) so all 4
//   grid-resident blocks/CU fit.
//   Kept (verified R2-R8): f16 z-pair packing + v_dot2_f32_f16 (R8, -5us),
//   12 ds_read_b128/px, quadrant waves + ZSTRIDE=132 (bank = 4s+cof mod 32,
//   conflict-free), zero local arrays / all-scalar compute (scratch-proof).

#define ZSTRIDE 132   // 9 cells * 12 ch = 108 dwords + 24 pad (132 % 32 == 4)

using half2v = decltype(__builtin_amdgcn_cvt_pkrtz(0.0f, 0.0f));

static __device__ __forceinline__ half2v pkrtz(float lo, float hi) {
    return __builtin_amdgcn_cvt_pkrtz(lo, hi);   // v_cvt_pkrtz_f16_f32
}
static __device__ __forceinline__ half2v u2h2(unsigned int u) {
    return __builtin_bit_cast(half2v, u);
}
static __device__ __forceinline__ unsigned int h2u(half2v h) {
    return __builtin_bit_cast(unsigned int, h);
}

#if __has_builtin(__builtin_amdgcn_fdot2)
#define DOT2(d, wp, acc) __builtin_amdgcn_fdot2(u2h2(d), (wp), (acc), false)
#else
// fallback: mixed-precision fma (compiler forms v_fma_mix_f32)
static __device__ __forceinline__ float dot2_sw(unsigned int d, half2v wp, float acc) {
    half2v h = u2h2(d);
    return fmaf((float)wp.x, (float)h.x, fmaf((float)wp.y, (float)h.y, acc));
}
#define DOT2(d, wp, acc) dot2_sw((d), (wp), (acc))
#endif

// one corner's 4-channel dual-z dot-accumulate (all scalar refs)
static __device__ __forceinline__ void corner_dot(
    const unsigned int* __restrict__ cp, half2v wp,
    float& a0, float& a1, float& a2, float& a3)
{
    const uint4 d = *reinterpret_cast<const uint4*>(cp);
    a0 = DOT2(d.x, wp, a0);
    a1 = DOT2(d.y, wp, a1);
    a2 = DOT2(d.z, wp, a2);
    a3 = DOT2(d.w, wp, a3);
}

// full per-pixel slice + apply; everything scalar (scratch-proof)
static __device__ __forceinline__ void px_eval(
    const unsigned int* __restrict__ lds,
    float g, float f0, float f1, float f2,
    float u0, float u1, float v0, float v1,
    int cof0, int cof1, int cof2, int cof3,
    float& o0, float& o1, float& o2)
{
    const float gz = g * 8.0f - 0.5f;
    int s = (int)floorf(gz);
    s = min(max(s, 0), 7);
    const float wz = fmaxf(gz - (float)s, 0.0f);
    const float zl = 1.0f - wz, zh = wz;
    const unsigned int* sb = &lds[s * ZSTRIDE];

    const float w00 = v0 * u0, w01 = v0 * u1;
    const float w10 = v1 * u0, w11 = v1 * u1;
    const half2v wp0 = pkrtz(w00 * zl, w00 * zh);
    const half2v wp1 = pkrtz(w01 * zl, w01 * zh);
    const half2v wp2 = pkrtz(w10 * zl, w10 * zh);
    const half2v wp3 = pkrtz(w11 * zl, w11 * zh);

    {
        float a0 = 0.f, a1 = 0.f, a2 = 0.f, a3 = 0.f;
        corner_dot(sb + cof0, wp0, a0, a1, a2, a3);
        corner_dot(sb + cof1, wp1, a0, a1, a2, a3);
        corner_dot(sb + cof2, wp2, a0, a1, a2, a3);
        corner_dot(sb + cof3, wp3, a0, a1, a2, a3);
        o0 = fmaf(a0, f0, fmaf(a1, f1, fmaf(a2, f2, a3)));
    }
    {
        float a0 = 0.f, a1 = 0.f, a2 = 0.f, a3 = 0.f;
        corner_dot(sb + cof0 + 4, wp0, a0, a1, a2, a3);
        corner_dot(sb + cof1 + 4, wp1, a0, a1, a2, a3);
        corner_dot(sb + cof2 + 4, wp2, a0, a1, a2, a3);
        corner_dot(sb + cof3 + 4, wp3, a0, a1, a2, a3);
        o1 = fmaf(a0, f0, fmaf(a1, f1, fmaf(a2, f2, a3)));
    }
    {
        float a0 = 0.f, a1 = 0.f, a2 = 0.f, a3 = 0.f;
        corner_dot(sb + cof0 + 8, wp0, a0, a1, a2, a3);
        corner_dot(sb + cof1 + 8, wp1, a0, a1, a2, a3);
        corner_dot(sb + cof2 + 8, wp2, a0, a1, a2, a3);
        corner_dot(sb + cof3 + 8, wp3, a0, a1, a2, a3);
        o2 = fmaf(a0, f0, fmaf(a1, f1, fmaf(a2, f2, a3)));
    }
}

__global__ __launch_bounds__(256, 4) void slice_apply(
    const float* __restrict__ grid,   // [4][12][8][16][16]
    const float* __restrict__ guide,  // [4][1][1024][1024]
    const float* __restrict__ fr,     // [4][3][1024][1024]
    float* __restrict__ out)          // [4][3][1024][1024]
{
    __shared__ __align__(16) unsigned int lds[8 * ZSTRIDE];

    const int b     = blockIdx.y;
    const int tileX = blockIdx.x & 15;
    const int tileY = blockIdx.x >> 4;
    const int t     = threadIdx.x;

    // ---- stage grid slice into LDS, z-pair packed as f16x2 ----
    {
        const int py0 = min(max(tileY - 1, 0), 15);
        const int py1 = tileY;
        const int py2 = min(tileY + 1, 15);
        const int px0 = min(max(tileX - 1, 0), 15);
        const int px1 = tileX;
        const int px2 = min(tileX + 1, 15);
        for (int e = t; e < 8 * 9 * 12; e += 256) {
            const int c    = e % 12;
            const int cell = (e / 12) % 9;
            const int s    = e / 108;
            const int s2   = min(s + 1, 7);
            const int gy3  = cell / 3;
            const int gx3  = cell % 3;
            const int ry = (gy3 == 0) ? py0 : ((gy3 == 1) ? py1 : py2);
            const int rx = (gx3 == 0) ? px0 : ((gx3 == 1) ? px1 : px2);
            const int cb = (b * 12 + c) * 8;
            const int sp = ry * 16 + rx;
            const float lo = grid[(cb + s)  * 256 + sp];
            const float hi = grid[(cb + s2) * 256 + sp];
            lds[s * ZSTRIDE + cell * 12 + c] = h2u(pkrtz(lo, hi));
        }
    }
    __syncthreads();

    // wave = quadrant (32x32 px); lane -> 2 adjacent-x px:
    //   16 lanes span x (float2), 4 sub-rows per iter, 8 iters.
    const int w   = t >> 6;
    const int l   = t & 63;
    const int by  = w >> 1;          // wave-uniform
    const int bx  = w & 1;           // wave-uniform
    const int lx2 = l & 15;          // x-pair index within quadrant
    const int sub = l >> 4;          // sub-row 0..3

    const int txA = bx * 32 + lx2 * 2;                  // tile-local x of px A
    const int xg  = tileX * 64 + txA;                   // global x (even)
    const float wxA = ((float)txA + 0.5f) * 0.015625f + (0.5f - (float)bx);
    const float wxB = wxA + 0.015625f;
    const float u1A = wxA, u0A = 1.0f - wxA;
    const float u1B = wxB, u0B = 1.0f - wxB;

    // corner dword offsets: four named scalars (NOT an array)
    const int cof0 = ((by + 0) * 3 + (bx + 0)) * 12;
    const int cof1 = ((by + 0) * 3 + (bx + 1)) * 12;
    const int cof2 = ((by + 1) * 3 + (bx + 0)) * 12;
    const int cof3 = ((by + 1) * 3 + (bx + 1)) * 12;

    // iter-0 addresses (row ly0 = by*32 + sub)
    const int y0   = tileY * 64 + by * 32 + sub;
    int gofs = (b * 1024 + y0) * 1024 + xg;
    int fofs = ((b * 3) * 1024 + y0) * 1024 + xg;

    // ---- prologue: load iteration 0 ----
    float2 gv  = *reinterpret_cast<const float2*>(guide + gofs);
    float2 f0v = *reinterpret_cast<const float2*>(fr + fofs);
    float2 f1v = *reinterpret_cast<const float2*>(fr + fofs + 1048576);
    float2 f2v = *reinterpret_cast<const float2*>(fr + fofs + 2097152);

    #pragma unroll
    for (int i = 0; i < 8; ++i) {
        // ---- issue next iteration's loads first (latency hiding) ----
        float2 gn = gv, f0n = f0v, f1n = f1v, f2n = f2v;
        if (i < 7) {
            const int gofs_n = gofs + 4 * 1024;   // +4 rows
            const int fofs_n = fofs + 4 * 1024;
            gn  = *reinterpret_cast<const float2*>(guide + gofs_n);
            f0n = *reinterpret_cast<const float2*>(fr + fofs_n);
            f1n = *reinterpret_cast<const float2*>(fr + fofs_n + 1048576);
            f2n = *reinterpret_cast<const float2*>(fr + fofs_n + 2097152);
        }

        // ---- compute current iteration ----
        const int ly = by * 32 + i * 4 + sub;     // tile-local y
        const float wy = ((float)ly + 0.5f) * 0.015625f + (0.5f - (float)by);
        const float v1 = wy, v0 = 1.0f - wy;

        float oA0, oA1, oA2, oB0, oB1, oB2;
        px_eval(lds, gv.x, f0v.x, f1v.x, f2v.x, u0A, u1A, v0, v1,
                cof0, cof1, cof2, cof3, oA0, oA1, oA2);
        px_eval(lds, gv.y, f0v.y, f1v.y, f2v.y, u0B, u1B, v0, v1,
                cof0, cof1, cof2, cof3, oB0, oB1, oB2);

        *reinterpret_cast<float2*>(out + fofs)           = make_float2(oA0, oB0);
        *reinterpret_cast<float2*>(out + fofs + 1048576) = make_float2(oA1, oB1);
        *reinterpret_cast<float2*>(out + fofs + 2097152) = make_float2(oA2, oB2);

        // ---- rotate ----
        gofs += 4 * 1024;
        fofs += 4 * 1024;
        gv = gn; f0v = f0n; f1v = f1n; f2v = f2n;
    }
}

extern "C" void kernel_launch(void* const* d_in, const int* in_sizes, int n_in,
                              void* d_out, int out_size, void* d_ws, size_t ws_size,
                              hipStream_t stream) {
    const float* grid  = (const float*)d_in[0];
    const float* guide = (const float*)d_in[1];
    const float* fr    = (const float*)d_in[2];
    float* out = (float*)d_out;

    dim3 g(256, 4);   // 16x16 tiles of 64x64 px, 4 batches
    dim3 blk(256);
    hipLaunchKernelGGL(slice_apply, g, blk, 0, stream, grid, guide, fr, out);
}